// Round 3
// baseline (621.603 us; speedup 1.0000x reference)
//
#include <hip/hip_runtime.h>
#include <math.h>

#define Bn 16
#define Cn 64
#define Hn 128
#define Wn 128
#define NPIX 16384
#define HIDN 4

// workspace offsets (floats)
#define WS_H     0
#define WS_W2B   16777216           // 64*4  (W2[c][0..2], b2[c])
#define WS_G0    (WS_W2B + 256)     // 4*8
#define WS_XM    (WS_G0 + 32)       // 16
#define WS_WTS   (WS_XM + 16)       // 4*16*64*6 = 24576
#define WS_AP    (WS_WTS + 24576)   // 16*4*64*64 = 262144 (per-hd, reused)
#define WS_BANDS (WS_AP + 262144)   // 262144
#define WS_CORR  (WS_BANDS + 262144)// 262144

__device__ __forceinline__ float mishf(float t) {
    // t * tanh(softplus(t)) == t * ((1+e^t)^2 - 1) / ((1+e^t)^2 + 1)
    float a = 1.0f + expf(fminf(t, 40.0f));
    a = a * a;
    return t * (a - 1.0f) / (a + 1.0f);
}

// ---- tiny prep: W2 = fc1_w@fc0_w, b2 = fc1_w@fc0_b + fc1_b; g0[hd][e] = label . Wg ----
__global__ void prep_kernel(const float* __restrict__ fc0_w, const float* __restrict__ fc0_b,
                            const float* __restrict__ fc1_w, const float* __restrict__ fc1_b,
                            const float* __restrict__ label, const float* __restrict__ Wg,
                            float* __restrict__ ws) {
    int t = threadIdx.x;
    if (t < 64) {
        int c = t;
        float a0 = 0.f, a1 = 0.f, a2 = 0.f, ab = 0.f;
        for (int k = 0; k < 64; ++k) {
            float f = fc1_w[c * 64 + k];
            a0 += f * fc0_w[k * 3 + 0];
            a1 += f * fc0_w[k * 3 + 1];
            a2 += f * fc0_w[k * 3 + 2];
            ab += f * fc0_b[k];
        }
        ws[WS_W2B + c * 4 + 0] = a0;
        ws[WS_W2B + c * 4 + 1] = a1;
        ws[WS_W2B + c * 4 + 2] = a2;
        ws[WS_W2B + c * 4 + 3] = ab + fc1_b[c];
    } else if (t < 96) {
        int idx = t - 64;           // hd*8+e
        int hd = idx >> 3, e = idx & 7;
        float s = 0.f;
        for (int l = 0; l < 8; ++l) s += label[l] * Wg[(hd * 8 + l) * 8 + e];
        ws[WS_G0 + idx] = s;
    }
}

// ---- xmean[b] ----
__global__ void xmean_kernel(const float* __restrict__ x, float* __restrict__ ws) {
    int b = blockIdx.x, t = threadIdx.x;
    float s = 0.f;
    for (int i = t; i < NPIX; i += 256) s += x[b * NPIX + i];
    for (int off = 32; off > 0; off >>= 1) s += __shfl_down(s, off);
    __shared__ float ps[4];
    if ((t & 63) == 0) ps[t >> 6] = s;
    __syncthreads();
    if (t == 0) ws[WS_XM + b] = (ps[0] + ps[1] + ps[2] + ps[3]) * (1.0f / NPIX);
}

// ---- gates: wts[hd][b][c][6] ----
__global__ void gates_kernel(const float* __restrict__ vg, float* __restrict__ ws) {
    int b = blockIdx.x, t = threadIdx.x;
    int c = t & 63, hd = t >> 6;
    const float* W2 = ws + WS_W2B + c * 4;
    float pooled = W2[0] * ws[WS_XM + b] + 0.5f * (W2[1] + W2[2]) + W2[3];
    float lg[8], m = -1e30f;
    for (int e = 0; e < 8; ++e) {
        lg[e] = ws[WS_G0 + hd * 8 + e] + pooled * vg[hd * 8 + e];
        m = fmaxf(m, lg[e]);
    }
    float s = 0.f;
    for (int e = 0; e < 8; ++e) { lg[e] = expf(lg[e] - m); s += lg[e]; }
    float inv = 1.0f / s;
    float* o = ws + WS_WTS + ((hd * 16 + b) * 64 + c) * 6;
    o[0] = lg[0] * inv; o[1] = lg[1] * inv; o[2] = lg[2] * inv;
    o[3] = lg[3] * inv; o[4] = (lg[4] + lg[6]) * inv; o[5] = (lg[5] + lg[7]) * inv;
}

// ---- stem: h = W2 . [x, gx, gy] + b2 ----
__global__ void h1_kernel(const float* __restrict__ x, float* __restrict__ ws) {
    int gid = blockIdx.x * 256 + threadIdx.x;
    int base = gid * 4;
    int b = base >> 20;
    int rem = base & 1048575;
    int c = rem >> 14;
    int pix = rem & 16383;
    int p = pix >> 7, q = pix & 127;
    const float* W2 = ws + WS_W2B + c * 4;
    float w0 = W2[0], w1 = W2[1], w2 = W2[2], bb = W2[3];
    float4 xv = *(const float4*)(x + b * NPIX + pix);
    float gx = p * (1.0f / 127.0f);
    float gy0 = q * (1.0f / 127.0f);
    const float step = 1.0f / 127.0f;
    float4 o;
    o.x = w0 * xv.x + w1 * gx + w2 * gy0 + bb;
    o.y = w0 * xv.y + w1 * gx + w2 * (gy0 + step) + bb;
    o.z = w0 * xv.z + w1 * gx + w2 * (gy0 + 2.f * step) + bb;
    o.w = w0 * xv.w + w1 * gx + w2 * (gy0 + 3.f * step) + bb;
    *(float4*)(ws + WS_H + base) = o;
}

// ---- per-layer: effective mixing matrices A'[b][k][i][o] ----
__global__ void ap_kernel(const float* __restrict__ exp_w, float* __restrict__ ws, int hd) {
    int flat = blockIdx.x * 256 + threadIdx.x;     // 1024*256 = 2^18
    int o = flat & 63;
    int i = (flat >> 6) & 63;
    int k = (flat >> 12) & 3;
    int b = flat >> 14;
    float acc = (i == o) ? -1.0f : 0.0f;
    const float* w = ws + WS_WTS + ((hd * 16 + b) * 64 + o) * 6;
    const float* ew = exp_w + (size_t)((hd * 8) * 4 + k) * 4096 + i * 64 + o;
    #pragma unroll
    for (int e = 0; e < 6; ++e) acc += w[e] * ew[(size_t)e * 16384];
    ws[WS_AP + flat] = acc;
}

// ---- per-layer: coarsest-band extraction (8x8 blocksums -> 4 bands) ----
__global__ void bands_kernel(const float* __restrict__ hbuf, float* __restrict__ ws) {
    int bi = blockIdx.x;            // 1024
    int b = bi >> 6, c = bi & 63;
    int t = threadIdx.x;
    __shared__ float R[128][17];    // 8-col-group sums per row
    __shared__ float S[16][17];     // 8x8 block sums
    const float* plane = hbuf + (size_t)(b * 64 + c) * NPIX;
    for (int rb = 0; rb < 8; ++rb) {
        const float* p4 = plane + rb * 2048 + t * 8;
        float4 a = *(const float4*)p4;
        float4 bb = *(const float4*)(p4 + 4);
        R[rb * 16 + (t >> 4)][t & 15] = a.x + a.y + a.z + a.w + bb.x + bb.y + bb.z + bb.w;
    }
    __syncthreads();
    {
        int rb2 = t >> 4, g = t & 15;
        float s = 0.f;
        #pragma unroll
        for (int k = 0; k < 8; ++k) s += R[rb2 * 8 + k][g];
        S[rb2][g] = s;
    }
    __syncthreads();
    if (t < 64) {
        int X = t >> 3, Y = t & 7;
        float q00 = S[2 * X][2 * Y],     q01 = S[2 * X][2 * Y + 1];
        float q10 = S[2 * X + 1][2 * Y], q11 = S[2 * X + 1][2 * Y + 1];
        float* bd = ws + WS_BANDS + (size_t)b * 16384 + c * 64 + t;
        bd[0]     = (q00 + q01 + q10 + q11) * 0.0625f;  // a
        bd[4096]  = (q00 - q01 + q10 - q11) * 0.0625f;  // lh (col sign)
        bd[8192]  = (q00 + q01 - q10 - q11) * 0.0625f;  // hl (row sign)
        bd[12288] = (q00 - q01 - q10 + q11) * 0.0625f;  // hh
    }
}

// ---- per-layer: corr[b][k][o][xy] = sum_i A'[b][k][i][o] * bands[b][k][i][xy] ----
__global__ void mix_kernel(float* __restrict__ ws) {
    int bi = blockIdx.x;            // 64 = b*4+k
    int t = threadIdx.x;
    __shared__ float sA[64][65];    // A'[i][o]
    __shared__ float sB[64][64];    // bands[i][xy]
    const float* Ap = ws + WS_AP + (size_t)bi * 4096;
    const float* Bd = ws + WS_BANDS + (size_t)bi * 4096;
    for (int it = 0; it < 16; ++it) {
        int flat = it * 256 + t;
        sA[flat >> 6][flat & 63] = Ap[flat];
        sB[flat >> 6][flat & 63] = Bd[flat];
    }
    __syncthreads();
    int xy = t & 63, ob = (t >> 6) * 16;
    float acc[16];
    #pragma unroll
    for (int j = 0; j < 16; ++j) acc[j] = 0.f;
    for (int i = 0; i < 64; ++i) {
        float v = sB[i][xy];
        #pragma unroll
        for (int j = 0; j < 16; ++j) acc[j] = fmaf(sA[i][ob + j], v, acc[j]);
    }
    float* out = ws + WS_CORR + (size_t)bi * 4096 + xy;
    #pragma unroll
    for (int j = 0; j < 16; ++j) out[(ob + j) * 64] = acc[j];
}

// ---- per-layer main: h = act(h + W0 h + b0 + U(corr)) in place ----
// Weights fetched via wave-uniform scalar loads (readfirstlane'd row base) so
// the inner loop is v_fmac v,s,v with a single stride-1 ds_read per i.
__global__ void conv_kernel(float* __restrict__ hbuf, const float* __restrict__ ws,
                            const float* __restrict__ w0_w, const float* __restrict__ w0_b,
                            int hd, int act) {
    int bi = blockIdx.x;            // 4096
    int b = bi >> 8, r = bi & 255;
    int row = r >> 1, qh = (r & 1) * 64;
    int t = threadIdx.x;
    __shared__ float inT[64][65];
    __shared__ float corrv[64][8];
    {
        int px = t & 63, lane4 = t >> 6;
        for (int cc = 0; cc < 16; ++cc) {
            int c = cc * 4 + lane4;
            inT[c][px] = hbuf[(size_t)(b * 64 + c) * NPIX + row * 128 + qh + px];
        }
    }
    {
        int X = row >> 4;
        float si = ((row >> 3) & 1) ? -1.f : 1.f;
        for (int rep = 0; rep < 2; ++rep) {
            int idx = rep * 256 + t;
            int o = idx >> 3, qg = idx & 7;
            int Y = (r & 1) * 4 + (qg >> 1);
            float sj = (qg & 1) ? -1.f : 1.f;
            const float* cb = ws + WS_CORR + (size_t)b * 16384 + o * 64 + X * 8 + Y;
            float ca = cb[0], clh = cb[4096], chl = cb[8192], chh = cb[12288];
            corrv[o][qg] = w0_b[hd * 64 + o] +
                           0.0625f * (ca + sj * clh + si * chl + si * sj * chh);
        }
    }
    __syncthreads();
    int px = t & 63, ob = (t >> 6) * 16, qg = px >> 3;
    // wave-uniform weight base -> scalar loads
    int obs = __builtin_amdgcn_readfirstlane(ob);
    const float* Wrow = w0_w + (size_t)hd * 4096 + (size_t)obs * 64;
    float acc[16];
    #pragma unroll
    for (int j = 0; j < 16; ++j) acc[j] = inT[ob + j][px] + corrv[ob + j][qg];
    for (int i = 0; i < 64; ++i) {
        float v = inT[i][px];
        #pragma unroll
        for (int j = 0; j < 16; ++j) acc[j] = fmaf(Wrow[j * 64 + i], v, acc[j]);
    }
    #pragma unroll
    for (int j = 0; j < 16; ++j) {
        float vv = act ? mishf(acc[j]) : acc[j];
        hbuf[(size_t)(b * 64 + ob + j) * NPIX + row * 128 + qh + px] = vv;
    }
}

// ---- final: out = fc3( mish(fc2 h) ) ----
__global__ void final_kernel(const float* __restrict__ hbuf,
                             const float* __restrict__ fc2_w, const float* __restrict__ fc2_b,
                             const float* __restrict__ fc3_w, const float* __restrict__ fc3_b,
                             float* __restrict__ out) {
    int bi = blockIdx.x;            // 4096
    int b = bi >> 8, r = bi & 255;
    int base = r * 64;
    int t = threadIdx.x;
    __shared__ float inT[64][65];
    __shared__ float partial[4][64];
    {
        int px = t & 63, lane4 = t >> 6;
        for (int cc = 0; cc < 16; ++cc) {
            int c = cc * 4 + lane4;
            inT[c][px] = hbuf[(size_t)(b * 64 + c) * NPIX + base + px];
        }
    }
    __syncthreads();
    int px = t & 63, jb = (t >> 6) * 32;
    // wave-uniform weight base -> scalar loads
    int jbs = __builtin_amdgcn_readfirstlane(jb);
    const float* W = fc2_w + (size_t)jbs * 64;
    const float* B2 = fc2_b + jbs;
    const float* F3 = fc3_w + jbs;
    float acc[32];
    #pragma unroll
    for (int jj = 0; jj < 32; ++jj) acc[jj] = B2[jj];
    for (int i = 0; i < 64; ++i) {
        float v = inT[i][px];
        #pragma unroll
        for (int jj = 0; jj < 32; ++jj) acc[jj] = fmaf(W[jj * 64 + i], v, acc[jj]);
    }
    float accO = 0.f;
    #pragma unroll
    for (int jj = 0; jj < 32; ++jj) accO = fmaf(F3[jj], mishf(acc[jj]), accO);
    partial[t >> 6][px] = accO;
    __syncthreads();
    if (t < 64) {
        out[(size_t)b * NPIX + base + t] =
            partial[0][t] + partial[1][t] + partial[2][t] + partial[3][t] + fc3_b[0];
    }
}

extern "C" void kernel_launch(void* const* d_in, const int* in_sizes, int n_in,
                              void* d_out, int out_size, void* d_ws, size_t ws_size,
                              hipStream_t stream) {
    const float* x      = (const float*)d_in[0];
    const float* label  = (const float*)d_in[1];
    const float* fc0_w  = (const float*)d_in[2];
    const float* fc0_b  = (const float*)d_in[3];
    const float* fc1_w  = (const float*)d_in[4];
    const float* fc1_b  = (const float*)d_in[5];
    const float* gate_Wg = (const float*)d_in[6];
    const float* gate_vg = (const float*)d_in[7];
    const float* exp_w  = (const float*)d_in[8];
    const float* w0_w   = (const float*)d_in[9];
    const float* w0_b   = (const float*)d_in[10];
    const float* fc2_w  = (const float*)d_in[11];
    const float* fc2_b  = (const float*)d_in[12];
    const float* fc3_w  = (const float*)d_in[13];
    const float* fc3_b  = (const float*)d_in[14];
    float* out = (float*)d_out;
    float* ws = (float*)d_ws;
    float* hbuf = ws + WS_H;

    prep_kernel<<<1, 256, 0, stream>>>(fc0_w, fc0_b, fc1_w, fc1_b, label, gate_Wg, ws);
    xmean_kernel<<<16, 256, 0, stream>>>(x, ws);
    gates_kernel<<<16, 256, 0, stream>>>(gate_vg, ws);
    h1_kernel<<<16384, 256, 0, stream>>>(x, ws);
    for (int hd = 0; hd < HIDN; ++hd) {
        ap_kernel<<<1024, 256, 0, stream>>>(exp_w, ws, hd);
        bands_kernel<<<1024, 256, 0, stream>>>(hbuf, ws);
        mix_kernel<<<64, 256, 0, stream>>>(ws);
        conv_kernel<<<4096, 256, 0, stream>>>(hbuf, ws, w0_w, w0_b, hd, hd != HIDN - 1);
    }
    final_kernel<<<4096, 256, 0, stream>>>(hbuf, fc2_w, fc2_b, fc3_w, fc3_b, out);
}

// Round 6
// 430.057 us; speedup vs baseline: 1.4454x; 1.4454x over previous
//
#include <hip/hip_runtime.h>
#include <math.h>

#define Bn 16
#define Cn 64
#define Hn 128
#define Wn 128
#define NPIX 16384
#define HIDN 4

typedef unsigned short ushort_t;
typedef short bf16x8 __attribute__((ext_vector_type(8)));
typedef float f32x4 __attribute__((ext_vector_type(4)));
#define MFMA16 __builtin_amdgcn_mfma_f32_16x16x32_bf16

// workspace offsets (floats)
#define WS_H     0
#define WS_W2B   16777216           // 64*4  (W2[c][0..2], b2[c])
#define WS_G0    (WS_W2B + 256)     // 4*8
#define WS_XM    (WS_G0 + 32)       // 16
#define WS_WTS   (WS_XM + 16)       // 4*16*64*6 = 24576
#define WS_AP    (WS_WTS + 24576)   // 16*4*64*64 = 262144 (per-hd, reused)
#define WS_BANDS (WS_AP + 262144)   // 262144
#define WS_CORR  (WS_BANDS + 262144)// 262144

__device__ __forceinline__ float mishf(float t) {
    float a = 1.0f + expf(fminf(t, 40.0f));
    a = a * a;
    return t * (a - 1.0f) / (a + 1.0f);
}

// round-to-nearest-even fp32 -> bf16 split: x ~= hi + lo
__device__ __forceinline__ void split_bf16(float x, ushort_t& hi, ushort_t& lo) {
    unsigned u = __float_as_uint(x);
    unsigned r = (u + 0x7FFFu + ((u >> 16) & 1u)) >> 16;
    hi = (ushort_t)r;
    float hf = __uint_as_float(r << 16);
    float l = x - hf;
    unsigned ul = __float_as_uint(l);
    lo = (ushort_t)((ul + 0x7FFFu + ((ul >> 16) & 1u)) >> 16);
}

// ---- tiny prep ----
__global__ void prep_kernel(const float* __restrict__ fc0_w, const float* __restrict__ fc0_b,
                            const float* __restrict__ fc1_w, const float* __restrict__ fc1_b,
                            const float* __restrict__ label, const float* __restrict__ Wg,
                            float* __restrict__ ws) {
    int t = threadIdx.x;
    if (t < 64) {
        int c = t;
        float a0 = 0.f, a1 = 0.f, a2 = 0.f, ab = 0.f;
        for (int k = 0; k < 64; ++k) {
            float f = fc1_w[c * 64 + k];
            a0 += f * fc0_w[k * 3 + 0];
            a1 += f * fc0_w[k * 3 + 1];
            a2 += f * fc0_w[k * 3 + 2];
            ab += f * fc0_b[k];
        }
        ws[WS_W2B + c * 4 + 0] = a0;
        ws[WS_W2B + c * 4 + 1] = a1;
        ws[WS_W2B + c * 4 + 2] = a2;
        ws[WS_W2B + c * 4 + 3] = ab + fc1_b[c];
    } else if (t < 96) {
        int idx = t - 64;           // hd*8+e
        int hd = idx >> 3, e = idx & 7;
        float s = 0.f;
        for (int l = 0; l < 8; ++l) s += label[l] * Wg[(hd * 8 + l) * 8 + e];
        ws[WS_G0 + idx] = s;
    }
}

// ---- xmean[b] ----
__global__ void xmean_kernel(const float* __restrict__ x, float* __restrict__ ws) {
    int b = blockIdx.x, t = threadIdx.x;
    float s = 0.f;
    for (int i = t; i < NPIX; i += 256) s += x[b * NPIX + i];
    for (int off = 32; off > 0; off >>= 1) s += __shfl_down(s, off);
    __shared__ float ps[4];
    if ((t & 63) == 0) ps[t >> 6] = s;
    __syncthreads();
    if (t == 0) ws[WS_XM + b] = (ps[0] + ps[1] + ps[2] + ps[3]) * (1.0f / NPIX);
}

// ---- gates: wts[hd][b][c][6] ----
__global__ void gates_kernel(const float* __restrict__ vg, float* __restrict__ ws) {
    int b = blockIdx.x, t = threadIdx.x;
    int c = t & 63, hd = t >> 6;
    const float* W2 = ws + WS_W2B + c * 4;
    float pooled = W2[0] * ws[WS_XM + b] + 0.5f * (W2[1] + W2[2]) + W2[3];
    float lg[8], m = -1e30f;
    for (int e = 0; e < 8; ++e) {
        lg[e] = ws[WS_G0 + hd * 8 + e] + pooled * vg[hd * 8 + e];
        m = fmaxf(m, lg[e]);
    }
    float s = 0.f;
    for (int e = 0; e < 8; ++e) { lg[e] = expf(lg[e] - m); s += lg[e]; }
    float inv = 1.0f / s;
    float* o = ws + WS_WTS + ((hd * 16 + b) * 64 + c) * 6;
    o[0] = lg[0] * inv; o[1] = lg[1] * inv; o[2] = lg[2] * inv;
    o[3] = lg[3] * inv; o[4] = (lg[4] + lg[6]) * inv; o[5] = (lg[5] + lg[7]) * inv;
}

// ---- stem: h = W2 . [x, gx, gy] + b2 ----
__global__ void h1_kernel(const float* __restrict__ x, float* __restrict__ ws) {
    int gid = blockIdx.x * 256 + threadIdx.x;
    int base = gid * 4;
    int b = base >> 20;
    int rem = base & 1048575;
    int c = rem >> 14;
    int pix = rem & 16383;
    int p = pix >> 7, q = pix & 127;
    const float* W2 = ws + WS_W2B + c * 4;
    float w0 = W2[0], w1 = W2[1], w2 = W2[2], bb = W2[3];
    float4 xv = *(const float4*)(x + b * NPIX + pix);
    float gx = p * (1.0f / 127.0f);
    float gy0 = q * (1.0f / 127.0f);
    const float step = 1.0f / 127.0f;
    float4 o;
    o.x = w0 * xv.x + w1 * gx + w2 * gy0 + bb;
    o.y = w0 * xv.y + w1 * gx + w2 * (gy0 + step) + bb;
    o.z = w0 * xv.z + w1 * gx + w2 * (gy0 + 2.f * step) + bb;
    o.w = w0 * xv.w + w1 * gx + w2 * (gy0 + 3.f * step) + bb;
    *(float4*)(ws + WS_H + base) = o;
}

// ---- per-layer: effective mixing matrices A'[b][k][i][o] ----
__global__ void ap_kernel(const float* __restrict__ exp_w, float* __restrict__ ws, int hd) {
    int flat = blockIdx.x * 256 + threadIdx.x;     // 2^18
    int o = flat & 63;
    int i = (flat >> 6) & 63;
    int k = (flat >> 12) & 3;
    int b = flat >> 14;
    float acc = (i == o) ? -1.0f : 0.0f;
    const float* w = ws + WS_WTS + ((hd * 16 + b) * 64 + o) * 6;
    const float* ew = exp_w + (size_t)((hd * 8) * 4 + k) * 4096 + i * 64 + o;
    #pragma unroll
    for (int e = 0; e < 6; ++e) acc += w[e] * ew[(size_t)e * 16384];
    ws[WS_AP + flat] = acc;
}

// ---- per-layer: coarsest-band extraction ----
__global__ void bands_kernel(const float* __restrict__ hbuf, float* __restrict__ ws) {
    int bi = blockIdx.x;            // 1024
    int b = bi >> 6, c = bi & 63;
    int t = threadIdx.x;
    __shared__ float R[128][17];
    __shared__ float S[16][17];
    const float* plane = hbuf + (size_t)(b * 64 + c) * NPIX;
    for (int rb = 0; rb < 8; ++rb) {
        const float* p4 = plane + rb * 2048 + t * 8;
        float4 a = *(const float4*)p4;
        float4 bb = *(const float4*)(p4 + 4);
        R[rb * 16 + (t >> 4)][t & 15] = a.x + a.y + a.z + a.w + bb.x + bb.y + bb.z + bb.w;
    }
    __syncthreads();
    {
        int rb2 = t >> 4, g = t & 15;
        float s = 0.f;
        #pragma unroll
        for (int k = 0; k < 8; ++k) s += R[rb2 * 8 + k][g];
        S[rb2][g] = s;
    }
    __syncthreads();
    if (t < 64) {
        int X = t >> 3, Y = t & 7;
        float q00 = S[2 * X][2 * Y],     q01 = S[2 * X][2 * Y + 1];
        float q10 = S[2 * X + 1][2 * Y], q11 = S[2 * X + 1][2 * Y + 1];
        float* bd = ws + WS_BANDS + (size_t)b * 16384 + c * 64 + t;
        bd[0]     = (q00 + q01 + q10 + q11) * 0.0625f;
        bd[4096]  = (q00 - q01 + q10 - q11) * 0.0625f;
        bd[8192]  = (q00 + q01 - q10 - q11) * 0.0625f;
        bd[12288] = (q00 - q01 - q10 + q11) * 0.0625f;
    }
}

// ---- per-layer: corr[b][k][o][xy] = sum_i A'[b][k][i][o] * bands[b][k][i][xy] ----
__global__ void mix_kernel(float* __restrict__ ws) {
    int bi = blockIdx.x;            // 64 = b*4+k
    int t = threadIdx.x;
    __shared__ float sA[64][65];
    __shared__ float sB[64][64];
    const float* Ap = ws + WS_AP + (size_t)bi * 4096;
    const float* Bd = ws + WS_BANDS + (size_t)bi * 4096;
    for (int it = 0; it < 16; ++it) {
        int flat = it * 256 + t;
        sA[flat >> 6][flat & 63] = Ap[flat];
        sB[flat >> 6][flat & 63] = Bd[flat];
    }
    __syncthreads();
    int xy = t & 63, ob = (t >> 6) * 16;
    float acc[16];
    #pragma unroll
    for (int j = 0; j < 16; ++j) acc[j] = 0.f;
    for (int i = 0; i < 64; ++i) {
        float v = sB[i][xy];
        #pragma unroll
        for (int j = 0; j < 16; ++j) acc[j] = fmaf(sA[i][ob + j], v, acc[j]);
    }
    float* out = ws + WS_CORR + (size_t)bi * 4096 + xy;
    #pragma unroll
    for (int j = 0; j < 16; ++j) out[(ob + j) * 64] = acc[j];
}

// ---- per-layer main (MFMA): h = act( (W0+I) h + b0 + U(corr) ) in place ----
// bf16x3 split GEMM: C = Whi*hhi + Whi*hlo + Wlo*hhi (fp32-class accuracy).
__global__ void __launch_bounds__(256) conv_mfma(
        float* __restrict__ hbuf, const float* __restrict__ ws,
        const float* __restrict__ w0_w, const float* __restrict__ w0_b,
        int hd, int act) {
    int bi = blockIdx.x;            // 4096
    int b = bi >> 8, r = bi & 255;
    int row = r >> 1, qh = (r & 1) * 64;
    int t = threadIdx.x;
    __shared__ short sBhi[64][72];  // h tile, [px][i]
    __shared__ short sBlo[64][72];
    __shared__ short sAhi[64][72];  // W0', [o][i]
    __shared__ short sAlo[64][72];
    __shared__ float sCorr[8][64];  // [qg][o]  (qg = px>>3 within the 64-px tile)

    const float* hbase = hbuf + (size_t)b * 64 * NPIX + row * 128 + qh;
    // stage h tile (64 ch x 64 px), split to bf16 hi/lo, transpose to [px][i]
    {
        int px = t & 63, cg = t >> 6;
        for (int rep = 0; rep < 8; ++rep) {
            int c0 = rep * 8 + cg * 2;
            float v0 = hbase[(size_t)c0 * NPIX + px];
            float v1 = hbase[(size_t)(c0 + 1) * NPIX + px];
            ushort_t h0, l0, h1, l1;
            split_bf16(v0, h0, l0);
            split_bf16(v1, h1, l1);
            *(unsigned*)&sBhi[px][c0] = (unsigned)h0 | ((unsigned)h1 << 16);
            *(unsigned*)&sBlo[px][c0] = (unsigned)l0 | ((unsigned)l1 << 16);
        }
    }
    // stage W0' = W0 + I, split
    {
        const float* wb = w0_w + (size_t)hd * 4096;
        for (int rep = 0; rep < 8; ++rep) {
            int f = rep * 256 + t;          // 2048 dword-pairs
            int o = f >> 5, i0 = (f & 31) * 2;
            float w0v = wb[o * 64 + i0]     + ((o == i0)     ? 1.0f : 0.0f);
            float w1v = wb[o * 64 + i0 + 1] + ((o == i0 + 1) ? 1.0f : 0.0f);
            ushort_t h0, l0, h1, l1;
            split_bf16(w0v, h0, l0);
            split_bf16(w1v, h1, l1);
            *(unsigned*)&sAhi[o][i0] = (unsigned)h0 | ((unsigned)h1 << 16);
            *(unsigned*)&sAlo[o][i0] = (unsigned)l0 | ((unsigned)l1 << 16);
        }
    }
    // stage corrT[qg][o] = b0[o] + U-weights . corr bands
    {
        int X = row >> 4;
        float si = ((row >> 3) & 1) ? -1.f : 1.f;
        for (int rep = 0; rep < 2; ++rep) {
            int idx = rep * 256 + t;        // 512
            int o = idx & 63, qg = idx >> 6;
            int Y = (r & 1) * 4 + (qg >> 1);
            float sj = (qg & 1) ? -1.f : 1.f;
            const float* cb = ws + WS_CORR + (size_t)b * 16384 + o * 64 + X * 8 + Y;
            sCorr[qg][o] = w0_b[hd * 64 + o] +
                           0.0625f * (cb[0] + sj * cb[4096] + si * cb[8192] + si * sj * cb[12288]);
        }
    }
    __syncthreads();

    int w = t >> 6, l = t & 63;
    int lr = l & 15, lk = l >> 4;           // in-tile index / k-octet
    int px = 16 * w + lr;
    bf16x8 Bh0 = *(const bf16x8*)&sBhi[px][8 * lk];
    bf16x8 Bh1 = *(const bf16x8*)&sBhi[px][32 + 8 * lk];
    bf16x8 Bl0 = *(const bf16x8*)&sBlo[px][8 * lk];
    bf16x8 Bl1 = *(const bf16x8*)&sBlo[px][32 + 8 * lk];
    int qg = px >> 3;
    float* outp = hbuf + (size_t)(b * 64 + 4 * lk) * NPIX + row * 128 + qh + px;
    #pragma unroll
    for (int m = 0; m < 4; ++m) {
        int o0 = 16 * m + lr;
        bf16x8 Ah0 = *(const bf16x8*)&sAhi[o0][8 * lk];
        bf16x8 Ah1 = *(const bf16x8*)&sAhi[o0][32 + 8 * lk];
        bf16x8 Al0 = *(const bf16x8*)&sAlo[o0][8 * lk];
        bf16x8 Al1 = *(const bf16x8*)&sAlo[o0][32 + 8 * lk];
        f32x4 a = {0.f, 0.f, 0.f, 0.f};
        a = MFMA16(Ah0, Bh0, a, 0, 0, 0);
        a = MFMA16(Ah1, Bh1, a, 0, 0, 0);
        a = MFMA16(Ah0, Bl0, a, 0, 0, 0);
        a = MFMA16(Ah1, Bl1, a, 0, 0, 0);
        a = MFMA16(Al0, Bh0, a, 0, 0, 0);
        a = MFMA16(Al1, Bh1, a, 0, 0, 0);
        float4 c4 = *(const float4*)&sCorr[qg][16 * m + 4 * lk];
        float cv[4] = {c4.x, c4.y, c4.z, c4.w};
        #pragma unroll
        for (int rr = 0; rr < 4; ++rr) {
            float v = a[rr] + cv[rr];
            if (act) v = mishf(v);
            outp[(size_t)(16 * m + rr) * NPIX] = v;
        }
    }
}

// ---- final (MFMA): out = fc3 . mish(fc2 h + b2f) + b3 ----
__global__ void __launch_bounds__(256) final_mfma(
        const float* __restrict__ hbuf,
        const float* __restrict__ fc2_w, const float* __restrict__ fc2_b,
        const float* __restrict__ fc3_w, const float* __restrict__ fc3_b,
        float* __restrict__ out) {
    int bi = blockIdx.x;            // 4096
    int b = bi >> 8, r = bi & 255;
    int row = r >> 1, qh = (r & 1) * 64;
    int t = threadIdx.x;
    __shared__ short sBhi[64][72];   // h tile [px][i]
    __shared__ short sBlo[64][72];
    __shared__ short sWhi[128][72];  // fc2 [j][i]
    __shared__ short sWlo[128][72];
    __shared__ float sB2[128];
    __shared__ float sF3[128];

    const float* hbase = hbuf + (size_t)b * 64 * NPIX + row * 128 + qh;
    {
        int px = t & 63, cg = t >> 6;
        for (int rep = 0; rep < 8; ++rep) {
            int c0 = rep * 8 + cg * 2;
            float v0 = hbase[(size_t)c0 * NPIX + px];
            float v1 = hbase[(size_t)(c0 + 1) * NPIX + px];
            ushort_t h0, l0, h1, l1;
            split_bf16(v0, h0, l0);
            split_bf16(v1, h1, l1);
            *(unsigned*)&sBhi[px][c0] = (unsigned)h0 | ((unsigned)h1 << 16);
            *(unsigned*)&sBlo[px][c0] = (unsigned)l0 | ((unsigned)l1 << 16);
        }
    }
    {
        for (int rep = 0; rep < 16; ++rep) {
            int f = rep * 256 + t;          // 4096 dword-pairs
            int j = f >> 5, i0 = (f & 31) * 2;
            float w0v = fc2_w[j * 64 + i0];
            float w1v = fc2_w[j * 64 + i0 + 1];
            ushort_t h0, l0, h1, l1;
            split_bf16(w0v, h0, l0);
            split_bf16(w1v, h1, l1);
            *(unsigned*)&sWhi[j][i0] = (unsigned)h0 | ((unsigned)h1 << 16);
            *(unsigned*)&sWlo[j][i0] = (unsigned)l0 | ((unsigned)l1 << 16);
        }
        if (t < 128) { sB2[t] = fc2_b[t]; sF3[t] = fc3_w[t]; }
    }
    __syncthreads();

    int w = t >> 6, l = t & 63;
    int lr = l & 15, lk = l >> 4;
    int px = 16 * w + lr;
    bf16x8 Bh0 = *(const bf16x8*)&sBhi[px][8 * lk];
    bf16x8 Bh1 = *(const bf16x8*)&sBhi[px][32 + 8 * lk];
    bf16x8 Bl0 = *(const bf16x8*)&sBlo[px][8 * lk];
    bf16x8 Bl1 = *(const bf16x8*)&sBlo[px][32 + 8 * lk];
    float partial = 0.f;
    #pragma unroll
    for (int m = 0; m < 8; ++m) {
        int j0 = 16 * m + lr;
        bf16x8 Ah0 = *(const bf16x8*)&sWhi[j0][8 * lk];
        bf16x8 Ah1 = *(const bf16x8*)&sWhi[j0][32 + 8 * lk];
        bf16x8 Al0 = *(const bf16x8*)&sWlo[j0][8 * lk];
        bf16x8 Al1 = *(const bf16x8*)&sWlo[j0][32 + 8 * lk];
        f32x4 a = {0.f, 0.f, 0.f, 0.f};
        a = MFMA16(Ah0, Bh0, a, 0, 0, 0);
        a = MFMA16(Ah1, Bh1, a, 0, 0, 0);
        a = MFMA16(Ah0, Bl0, a, 0, 0, 0);
        a = MFMA16(Ah1, Bl1, a, 0, 0, 0);
        a = MFMA16(Al0, Bh0, a, 0, 0, 0);
        a = MFMA16(Al1, Bh1, a, 0, 0, 0);
        float4 b4 = *(const float4*)&sB2[16 * m + 4 * lk];
        float4 f4 = *(const float4*)&sF3[16 * m + 4 * lk];
        float bv[4] = {b4.x, b4.y, b4.z, b4.w};
        float fv[4] = {f4.x, f4.y, f4.z, f4.w};
        #pragma unroll
        for (int rr = 0; rr < 4; ++rr)
            partial = fmaf(fv[rr], mishf(a[rr] + bv[rr]), partial);
    }
    partial += __shfl_xor(partial, 16, 64);
    partial += __shfl_xor(partial, 32, 64);
    if (lk == 0)
        out[(size_t)b * NPIX + row * 128 + qh + px] = partial + fc3_b[0];
}

extern "C" void kernel_launch(void* const* d_in, const int* in_sizes, int n_in,
                              void* d_out, int out_size, void* d_ws, size_t ws_size,
                              hipStream_t stream) {
    const float* x      = (const float*)d_in[0];
    const float* label  = (const float*)d_in[1];
    const float* fc0_w  = (const float*)d_in[2];
    const float* fc0_b  = (const float*)d_in[3];
    const float* fc1_w  = (const float*)d_in[4];
    const float* fc1_b  = (const float*)d_in[5];
    const float* gate_Wg = (const float*)d_in[6];
    const float* gate_vg = (const float*)d_in[7];
    const float* exp_w  = (const float*)d_in[8];
    const float* w0_w   = (const float*)d_in[9];
    const float* w0_b   = (const float*)d_in[10];
    const float* fc2_w  = (const float*)d_in[11];
    const float* fc2_b  = (const float*)d_in[12];
    const float* fc3_w  = (const float*)d_in[13];
    const float* fc3_b  = (const float*)d_in[14];
    float* out = (float*)d_out;
    float* ws = (float*)d_ws;
    float* hbuf = ws + WS_H;

    prep_kernel<<<1, 256, 0, stream>>>(fc0_w, fc0_b, fc1_w, fc1_b, label, gate_Wg, ws);
    xmean_kernel<<<16, 256, 0, stream>>>(x, ws);
    gates_kernel<<<16, 256, 0, stream>>>(gate_vg, ws);
    h1_kernel<<<16384, 256, 0, stream>>>(x, ws);
    for (int hd = 0; hd < HIDN; ++hd) {
        ap_kernel<<<1024, 256, 0, stream>>>(exp_w, ws, hd);
        bands_kernel<<<1024, 256, 0, stream>>>(hbuf, ws);
        mix_kernel<<<64, 256, 0, stream>>>(ws);
        conv_mfma<<<4096, 256, 0, stream>>>(hbuf, ws, w0_w, w0_b, hd, hd != HIDN - 1);
    }
    final_mfma<<<4096, 256, 0, stream>>>(hbuf, fc2_w, fc2_b, fc3_w, fc3_b, out);
}